// Round 9
// baseline (57.105 us; speedup 1.0000x reference)
//
#include <hip/hip_runtime.h>
#include <math.h>

#define C2 2.8853900817779268f   // 2*log2(e)

// prep: EkT[b][t8][hh2][g16][k32][hi4] = exp2(C2 * K[b][k=t*32+k32][h=hh*64+g*4+hi])
// One 32-k-row tile = 4096 floats (16 KB) contiguous -> main kernel stages linearly.
__global__ __launch_bounds__(512) void addattn_prep(const float* __restrict__ k_g,
                                                    float* __restrict__ ekt)
{
    int tid = blockIdx.x * 512 + threadIdx.x;   // 262144 threads
    int b   = tid >> 13;
    int r   = tid & 8191;
    int h4  = r >> 8;           // 0..31 (h-group of 4)
    int k   = r & 255;          // 0..255
    float4 kv = *(const float4*)(k_g + ((size_t)(b * 256 + k)) * 128 + (h4 << 2));
    float4 E;
    E.x = __builtin_amdgcn_exp2f(C2 * kv.x);
    E.y = __builtin_amdgcn_exp2f(C2 * kv.y);
    E.z = __builtin_amdgcn_exp2f(C2 * kv.z);
    E.w = __builtin_amdgcn_exp2f(C2 * kv.w);
    *(float4*)(ekt + (size_t)b * 32768 + ((k >> 5) << 12) + ((h4 >> 4) << 11)
               + ((h4 & 15) << 7) + ((k & 31) << 2)) = E;
}

// main: 512 blocks x 256 thr (4 waves). Wave = 4 q rows (register-blocked).
// Lane = (hh = h-half, kk = k-within-tile). 2 blocks/CU for barrier overlap.
__global__ __launch_bounds__(256, 2) void addattn_kernel(
    const float* __restrict__ q_g, const float* __restrict__ ekt,
    const float* __restrict__ v_g, const float* __restrict__ w_g,
    float* __restrict__ out)
{
    __shared__ float dbuf[8192];    // 32 KB: 2 x 16KB double-buffered 32-k-row tiles (Ek, then V)
    __shared__ float sattn[4096];   // 16 KB: per-wave [4 rows][256] scores -> attn (in place)
    __shared__ float eqst[2048];    //  8 KB: per-wave [4 rows][128] Eq
    __shared__ float wlds[128];     // 0.5 KB

    const int tid  = threadIdx.x;   // 0..255
    const int lane = tid & 63;
    const int wv   = tid >> 6;      // 0..3
    const int kk   = lane & 31;     // k within tile (score) / h-chunk (PV)
    const int hh   = lane >> 5;     // h-half (score) / k-half (PV)

    // XCD-grouped remap: 4 whole batches per XCD -> Ek/V/Q stay L2-hot
    const int o   = ((blockIdx.x & 7) << 6) + (blockIdx.x >> 3);
    const int b   = o >> 4;
    const int q0  = (o & 15) << 4;
    const int qr0 = q0 + (wv << 2);   // wave's first q row

    if (tid < 32) ((float4*)wlds)[tid] = ((const float4*)w_g)[tid];

    // Eq = exp2(C2*q) for the wave's 4 rows (2 float4 per lane)
    {
        const float* qb = q_g + (size_t)(b * 256 + qr0) * 128;
        #pragma unroll
        for (int j = 0; j < 2; ++j) {
            int f = lane + (j << 6);       // float4 index into [4 rows][32]
            int r = f >> 5, c = f & 31;
            float4 qv = *(const float4*)(qb + (r << 7) + (c << 2));
            float4 E;
            E.x = __builtin_amdgcn_exp2f(C2 * qv.x);
            E.y = __builtin_amdgcn_exp2f(C2 * qv.y);
            E.z = __builtin_amdgcn_exp2f(C2 * qv.z);
            E.w = __builtin_amdgcn_exp2f(C2 * qv.w);
            *(float4*)&eqst[(wv << 9) + (r << 7) + (c << 2)] = E;
        }
    }

    const float4* ek4 = (const float4*)(ekt + (size_t)b * 32768);
    const float4* vg4 = (const float4*)(v_g + (size_t)b * 32768);

    // stage Ek tile 0 (linear, coalesced)
    #pragma unroll
    for (int j = 0; j < 4; ++j)
        ((float4*)dbuf)[tid + (j << 8)] = ek4[tid + (j << 8)];
    __syncthreads();

    const float* eqp = eqst + (wv << 9) + (hh << 6);   // + r*128 + g*4
    const float* wb  = wlds + (hh << 6);               // + g*4
    float* srow = sattn + (wv << 10);                  // [r*256 + k]

    // ---- score phase: 8 tiles of 32 k, double-buffered, 4 rows amortize k-read ----
    #pragma unroll 1
    for (int t = 0; t < 8; ++t) {
        float4 p0, p1, p2, p3;
        if (t < 7) {
            p0 = ek4[((t + 1) << 10) + tid];
            p1 = ek4[((t + 1) << 10) + 256 + tid];
            p2 = ek4[((t + 1) << 10) + 512 + tid];
            p3 = ek4[((t + 1) << 10) + 768 + tid];
        }
        const float* kb = dbuf + ((t & 1) << 12) + (hh << 11) + (kk << 2);
        float s0 = 0.f, s1 = 0.f, s2 = 0.f, s3 = 0.f;
        #pragma unroll
        for (int g = 0; g < 16; ++g) {
            float4 k4 = *(const float4*)(kb + (g << 7));          // per-lane, conflict-free
            float4 w4 = *(const float4*)(wb + (g << 2));          // 2-addr broadcast
            float4 e0 = *(const float4*)(eqp + (g << 2));
            float4 e1 = *(const float4*)(eqp + 128 + (g << 2));
            float4 e2 = *(const float4*)(eqp + 256 + (g << 2));
            float4 e3 = *(const float4*)(eqp + 384 + (g << 2));
            #pragma unroll
            for (int i = 0; i < 4; ++i) {
                float kv = (&k4.x)[i], wi = (&w4.x)[i];
                float d0 = fmaf((&e0.x)[i], kv, 1.0f);
                float d1 = fmaf((&e1.x)[i], kv, 1.0f);
                float d2 = fmaf((&e2.x)[i], kv, 1.0f);
                float d3 = fmaf((&e3.x)[i], kv, 1.0f);
                s0 = fmaf(wi, __builtin_amdgcn_rcpf(d0), s0);
                s1 = fmaf(wi, __builtin_amdgcn_rcpf(d1), s1);
                s2 = fmaf(wi, __builtin_amdgcn_rcpf(d2), s2);
                s3 = fmaf(wi, __builtin_amdgcn_rcpf(d3), s3);
            }
        }
        s0 += __shfl_xor(s0, 32);      // combine h-halves
        s1 += __shfl_xor(s1, 32);
        s2 += __shfl_xor(s2, 32);
        s3 += __shfl_xor(s3, 32);
        if (hh == 0) {
            srow[(t << 5) + kk]       = -C2 * s0;
            srow[256 + (t << 5) + kk] = -C2 * s1;
            srow[512 + (t << 5) + kk] = -C2 * s2;
            srow[768 + (t << 5) + kk] = -C2 * s3;
        }
        if (t < 7) {
            float* d = dbuf + (((t + 1) & 1) << 12);
            ((float4*)d)[tid]       = p0;
            ((float4*)d)[tid + 256] = p1;
            ((float4*)d)[tid + 512] = p2;
            ((float4*)d)[tid + 768] = p3;
        }
        __syncthreads();
    }

    // ---- V tile 0 prefetch; softmax (4 rows, 64-lane each) overlaps the latency ----
    float4 pv0 = vg4[tid], pv1 = vg4[tid + 256], pv2 = vg4[tid + 512], pv3 = vg4[tid + 768];

    #pragma unroll
    for (int r = 0; r < 4; ++r) {
        float4 sv = *(const float4*)&srow[(r << 8) + (lane << 2)];
        float mx = fmaxf(fmaxf(sv.x, sv.y), fmaxf(sv.z, sv.w));
        #pragma unroll
        for (int off = 32; off; off >>= 1) mx = fmaxf(mx, __shfl_xor(mx, off));
        float ex = __builtin_amdgcn_exp2f(sv.x - mx);
        float ey = __builtin_amdgcn_exp2f(sv.y - mx);
        float ez = __builtin_amdgcn_exp2f(sv.z - mx);
        float ew = __builtin_amdgcn_exp2f(sv.w - mx);
        float sum = (ex + ey) + (ez + ew);
        #pragma unroll
        for (int off = 32; off; off >>= 1) sum += __shfl_xor(sum, off);
        float inv = __builtin_amdgcn_rcpf(sum);
        float4 at; at.x = ex * inv; at.y = ey * inv; at.z = ez * inv; at.w = ew * inv;
        *(float4*)&srow[(r << 8) + (lane << 2)] = at;   // attn in place (own-wave order)
    }

    ((float4*)dbuf)[tid]       = pv0;   // V tile 0 -> buffer 0, linear [32][128]
    ((float4*)dbuf)[tid + 256] = pv1;
    ((float4*)dbuf)[tid + 512] = pv2;
    ((float4*)dbuf)[tid + 768] = pv3;
    __syncthreads();

    // ---- PV phase: lane = h-chunk kk (h=4kk..+3), k-half hh; 4 rows in regs ----
    float4 a0, a1, a2, a3;
    a0.x = a0.y = a0.z = a0.w = 0.f;
    a1.x = a1.y = a1.z = a1.w = 0.f;
    a2.x = a2.y = a2.z = a2.w = 0.f;
    a3.x = a3.y = a3.z = a3.w = 0.f;
    #pragma unroll 1
    for (int t = 0; t < 8; ++t) {
        float4 p0, p1, p2, p3;
        if (t < 7) {
            p0 = vg4[((t + 1) << 10) + tid];
            p1 = vg4[((t + 1) << 10) + 256 + tid];
            p2 = vg4[((t + 1) << 10) + 512 + tid];
            p3 = vg4[((t + 1) << 10) + 768 + tid];
        }
        const float* vb = dbuf + ((t & 1) << 12) + (hh << 11) + (kk << 2);
        const float* ab = srow + (t << 5) + (hh << 4);
        #pragma unroll
        for (int g = 0; g < 4; ++g) {
            float4 t0 = *(const float4*)(ab + (g << 2));          // row attn (2-addr bcast)
            float4 t1 = *(const float4*)(ab + 256 + (g << 2));
            float4 t2 = *(const float4*)(ab + 512 + (g << 2));
            float4 t3 = *(const float4*)(ab + 768 + (g << 2));
            #pragma unroll
            for (int i = 0; i < 4; ++i) {
                float4 vv = *(const float4*)(vb + (((g << 2) + i) << 7));  // conflict-free
                float c0 = (&t0.x)[i], c1 = (&t1.x)[i], c2 = (&t2.x)[i], c3 = (&t3.x)[i];
                a0.x = fmaf(c0, vv.x, a0.x); a0.y = fmaf(c0, vv.y, a0.y);
                a0.z = fmaf(c0, vv.z, a0.z); a0.w = fmaf(c0, vv.w, a0.w);
                a1.x = fmaf(c1, vv.x, a1.x); a1.y = fmaf(c1, vv.y, a1.y);
                a1.z = fmaf(c1, vv.z, a1.z); a1.w = fmaf(c1, vv.w, a1.w);
                a2.x = fmaf(c2, vv.x, a2.x); a2.y = fmaf(c2, vv.y, a2.y);
                a2.z = fmaf(c2, vv.z, a2.z); a2.w = fmaf(c2, vv.w, a2.w);
                a3.x = fmaf(c3, vv.x, a3.x); a3.y = fmaf(c3, vv.y, a3.y);
                a3.z = fmaf(c3, vv.z, a3.z); a3.w = fmaf(c3, vv.w, a3.w);
            }
        }
        if (t < 7) {
            float* d = dbuf + (((t + 1) & 1) << 12);
            ((float4*)d)[tid]       = p0;
            ((float4*)d)[tid + 256] = p1;
            ((float4*)d)[tid + 512] = p2;
            ((float4*)d)[tid + 768] = p3;
            __syncthreads();
        }
    }

    // combine k-halves
    a0.x += __shfl_xor(a0.x, 32); a0.y += __shfl_xor(a0.y, 32);
    a0.z += __shfl_xor(a0.z, 32); a0.w += __shfl_xor(a0.w, 32);
    a1.x += __shfl_xor(a1.x, 32); a1.y += __shfl_xor(a1.y, 32);
    a1.z += __shfl_xor(a1.z, 32); a1.w += __shfl_xor(a1.w, 32);
    a2.x += __shfl_xor(a2.x, 32); a2.y += __shfl_xor(a2.y, 32);
    a2.z += __shfl_xor(a2.z, 32); a2.w += __shfl_xor(a2.w, 32);
    a3.x += __shfl_xor(a3.x, 32); a3.y += __shfl_xor(a3.y, 32);
    a3.z += __shfl_xor(a3.z, 32); a3.w += __shfl_xor(a3.w, 32);

    if (hh == 0) {
        float* ob = out + (size_t)(b * 256 + qr0) * 128 + (kk << 2);
        *(float4*)(ob)       = a0;
        *(float4*)(ob + 128) = a1;
        *(float4*)(ob + 256) = a2;
        *(float4*)(ob + 384) = a3;
    }
}

extern "C" void kernel_launch(void* const* d_in, const int* in_sizes, int n_in,
                              void* d_out, int out_size, void* d_ws, size_t ws_size,
                              hipStream_t stream) {
    const float* q = (const float*)d_in[0];
    const float* k = (const float*)d_in[1];
    const float* v = (const float*)d_in[2];
    const float* w = (const float*)d_in[3];
    float* out = (float*)d_out;
    float* ekt = (float*)d_ws;                 // 32*256*128*4 = 4 MB scratch
    addattn_prep<<<512, 512, 0, stream>>>(k, ekt);
    addattn_kernel<<<512, 256, 0, stream>>>(q, ekt, v, w, out);
}